// Round 1
// baseline (195.411 us; speedup 1.0000x reference)
//
#include <hip/hip_runtime.h>

// Problem constants (match reference)
#define BATCH   4096
#define DIM     64
#define NTOT    (BATCH * DIM * DIM)   // 16,777,216 fp32 per tensor
#define MRANK   32
#define GAMMA_C   0.1f
#define LAMBDA2_C 0.1f

// ---------------------------------------------------------------------------
// Kernel A: sum of (pred - true)^2 over all NTOT elements.
// Grid-stride float4 loads (16 B/lane), wave64 shuffle reduce, LDS block
// reduce, one atomicAdd per block into ws[0].
// ---------------------------------------------------------------------------
__global__ void __launch_bounds__(256)
sumsq_kernel(const float4* __restrict__ p, const float4* __restrict__ t,
             float* __restrict__ accum) {
    const int nvec = NTOT / 4;  // 4,194,304
    float acc = 0.0f;
    for (int i = blockIdx.x * blockDim.x + threadIdx.x; i < nvec;
         i += gridDim.x * blockDim.x) {
        float4 a = p[i];
        float4 b = t[i];
        float dx = a.x - b.x;
        float dy = a.y - b.y;
        float dz = a.z - b.z;
        float dw = a.w - b.w;
        acc += dx * dx + dy * dy + dz * dz + dw * dw;
    }
    // wave64 reduction
    #pragma unroll
    for (int off = 32; off > 0; off >>= 1)
        acc += __shfl_down(acc, off, 64);

    __shared__ float smem[4];  // 256 threads = 4 waves
    const int wid  = threadIdx.x >> 6;
    const int lane = threadIdx.x & 63;
    if (lane == 0) smem[wid] = acc;
    __syncthreads();
    if (threadIdx.x == 0) {
        float v = smem[0] + smem[1] + smem[2] + smem[3];
        atomicAdd(accum, v);
    }
}

// ---------------------------------------------------------------------------
// Kernel B: traces of first 32 matrices + pairwise rank loss + final outputs.
// One wave (64 threads). Lane i < 32 owns matrix i.
// ---------------------------------------------------------------------------
__global__ void __launch_bounds__(64)
finish_kernel(const float* __restrict__ p, const float* __restrict__ t,
              const float* __restrict__ sumsq, float* __restrict__ out) {
    const int lane = threadIdx.x;
    float tp = 0.0f, tt = 0.0f;
    if (lane < MRANK) {
        const float* pb = p + (size_t)lane * DIM * DIM;
        const float* tb = t + (size_t)lane * DIM * DIM;
        #pragma unroll
        for (int j = 0; j < DIM; ++j) {
            tp += pb[j * (DIM + 1)];
            tt += tb[j * (DIM + 1)];
        }
    }
    __shared__ float sp[MRANK], st[MRANK];
    if (lane < MRANK) { sp[lane] = tp; st[lane] = tt; }
    __syncthreads();

    float acc = 0.0f;
    if (lane < MRANK) {
        const float pi = sp[lane];
        const float ti = st[lane];
        for (int j = lane + 1; j < MRANK; ++j) {
            float dt = ti - st[j];
            float dp = pi - sp[j];
            float c = 0.0f;
            if (dt > 0.0f)      c = fmaxf(-dp + GAMMA_C, 0.0f);
            else if (dt < 0.0f) c = fmaxf( dp + GAMMA_C, 0.0f);
            acc += c;
        }
    }
    #pragma unroll
    for (int off = 32; off > 0; off >>= 1)
        acc += __shfl_down(acc, off, 64);

    if (lane == 0) {
        const float n_pairs = (float)(MRANK * (MRANK - 1) / 2);  // 496
        float rank = acc / n_pairs;
        float eff  = sumsq[0] / (float)NTOT;
        out[0] = eff + LAMBDA2_C * rank;  // total
        out[1] = eff;                     // efficiency_loss
        out[2] = rank;                    // rank_loss
    }
}

extern "C" void kernel_launch(void* const* d_in, const int* in_sizes, int n_in,
                              void* d_out, int out_size, void* d_ws, size_t ws_size,
                              hipStream_t stream) {
    const float* pred = (const float*)d_in[0];
    const float* tru  = (const float*)d_in[1];
    float* out = (float*)d_out;
    float* ws  = (float*)d_ws;

    // d_ws is poisoned with 0xAA before every call — zero the accumulator.
    hipMemsetAsync(ws, 0, sizeof(float), stream);

    const int threads = 256;
    const int blocks  = 2048;  // 8 blocks/CU, 8 float4 iters/thread
    sumsq_kernel<<<blocks, threads, 0, stream>>>(
        (const float4*)pred, (const float4*)tru, ws);

    finish_kernel<<<1, 64, 0, stream>>>(pred, tru, ws, out);
}